// Round 10
// baseline (150.364 us; speedup 1.0000x reference)
//
#include <hip/hip_runtime.h>

// out[n, :] = sum_{l=0..7} weight[l, x[n,l], :]
// N=131072, L=8, K=1024, D=1024; f32 in/out.
//
// Round 10: bf16 volume at f32 burst length. D split into 4 slices of 256
// cols; XCD pair (2s,2s+1) shares slice s (4 MB bf16 = full L2), xcd&1 picks
// the row-half. Gathered windows are 512 B (8 consecutive L2 lines) -- round
// 4 showed long bursts sustain ~19 lines/cyc/XCD vs ~16 for 256 B windows.
// Pipeline unchanged from round 9: global_load_lds width-16 DMA, 3 LDS
// buffers, prefetch depth 2, counted vmcnt, no main-loop barrier. Rotation
// ((l+k)&3)*256 cols spreads L2 channels. Consume: one wave per output row,
// 64 lanes x 4 cols; 1 KB contiguous NT stores.

#define N_ROWS 131072
#define L_DIM 8
#define K_DIM 1024
#define D_DIM 1024

#define RPB 64                       // output rows per block
#define CR 4                         // output rows per chunk
#define NCH (RPB / CR)               // 16 chunks
#define PFD 2                        // prefetch depth (chunks)
#define NBUF (PFD + 1)               // LDS buffers
#define CHB (CR * L_DIM * 512)       // bytes per chunk buffer = 16384
#define W_ELEMS (L_DIM * K_DIM * D_DIM)

typedef float        f32x4 __attribute__((ext_vector_type(4)));
typedef unsigned int u32x2 __attribute__((ext_vector_type(2)));

__device__ __forceinline__ unsigned short f2bf_rne(float f) {
    unsigned u = __float_as_uint(f);
    unsigned r = u + 0x7fffu + ((u >> 16) & 1u);   // round-to-nearest-even
    return (unsigned short)(r >> 16);
}
__device__ __forceinline__ float bflo(unsigned u) { return __uint_as_float(u << 16); }
__device__ __forceinline__ float bfhi(unsigned u) { return __uint_as_float(u & 0xffff0000u); }

__device__ __forceinline__ void load_lds16(const void* g, void* l) {
    __builtin_amdgcn_global_load_lds(
        (const __attribute__((address_space(1))) void*)g,
        (__attribute__((address_space(3))) void*)l,
        16, 0, 0);
}

template <int N>
__device__ __forceinline__ void vm_wait() {
    asm volatile("s_waitcnt vmcnt(%0)" :: "n"(N) : "memory");
    __builtin_amdgcn_sched_barrier(0);
}

// per-wave issue order per STEP: [4 loads][wait][1 store]
// newer than chunk c's loads: PFD chunks of 4 loads + up to PFD stores
constexpr int waitn(int c) {
    int nl = (c + PFD <= NCH - 1) ? PFD : (NCH - 1 - c);
    int ns = (c < PFD) ? c : PFD;
    return 4 * nl + ns;
}

// ---- pass 1: f32 weight -> rotated bf16 scratch ------------------------
__global__ __launch_bounds__(256) void convert_w_bf16(
    const float* __restrict__ w, unsigned short* __restrict__ wb)
{
    const int i = blockIdx.x * 256 + threadIdx.x;       // 4 floats per thread
    const f32x4 v = __builtin_nontemporal_load(
        reinterpret_cast<const f32x4*>(w) + i);
    ushort4 o;
    o.x = f2bf_rne(v.x); o.y = f2bf_rne(v.y);
    o.z = f2bf_rne(v.z); o.w = f2bf_rne(v.w);

    const int rk = i >> 8;                              // (l,k) row id
    const int c0 = (i & 255) * 4;                       // col of first elem
    const int l  = rk >> 10;
    const int k  = rk & 1023;
    const int r  = (l + k) & 3;
    const int c2 = (c0 + r * 256) & 1023;               // rotated col
    *reinterpret_cast<ushort4*>(wb + ((size_t)rk << 10) + c2) = o;
}

// ---- pass 2: barrier-free pipelined gather+sum, 512 B windows ----------
__global__ __launch_bounds__(256) void gather_sum_pipe(
    const int* __restrict__ x,
    const unsigned short* __restrict__ wb,
    float* __restrict__ out)
{
    __shared__ int sxi[RPB * L_DIM];                    // 2 KB indices
    __shared__ __align__(1024) char buf[NBUF * CHB];    // 3 x 16 KB

    const int xcd   = blockIdx.x & 7;                   // -> XCD id
    const int slice = xcd >> 1;                         // 4 col-slices of 256
    const int rowh  = xcd & 1;                          // row-half of chunk
    const int chunk = blockIdx.x >> 3;
    const int t     = threadIdx.x;
    const int n0    = chunk * 128 + rowh * RPB;
    const int col0  = slice * 256;

    if (t < RPB * L_DIM / 4)
        reinterpret_cast<int4*>(sxi)[t] =
            reinterpret_cast<const int4*>(x + (size_t)n0 * L_DIM)[t];
    __syncthreads();                                    // only barrier

    const int w_id = t >> 6;                            // wave 0..3
    const int lane = t & 63;
    const int grp  = lane >> 5;                         // window within pair
    const int sub  = lane & 31;                         // 16 B unit in window

    const char* __restrict__ wbytes = (const char*)wb;

    // chunk c holds rows [c*CR, c*CR+CR); wave w owns row c*CR + w entirely:
    // stages its 8 (l) windows of 512 B (4 DMA instrs x 2 windows) and
    // consumes them. Fully wave-self-contained -> no main-loop barrier.
    auto issue = [&](int c) {
        char* __restrict__ db = buf + (c % NBUF) * CHB + w_id * 4096;
        const int* __restrict__ xr = sxi + (c * CR + w_id) * L_DIM;
        #pragma unroll
        for (int i = 0; i < 4; ++i) {
            const int l = 2 * i + grp;
            const int k = xr[l];
            const int r = (slice + l + k) & 3;          // rotated window
            const unsigned off =
                ((unsigned)((l << 10) + k) << 11) + ((unsigned)r << 9)
                + (unsigned)sub * 16u;
            load_lds16(wbytes + off, db + i * 1024);
        }
    };

    auto consume = [&](int c) {
        const char* __restrict__ rb = buf + (c % NBUF) * CHB + w_id * 4096;
        u32x2 v[L_DIM];
        #pragma unroll
        for (int l = 0; l < L_DIM; ++l)
            v[l] = *reinterpret_cast<const u32x2*>(rb + l * 512 + lane * 8);
        f32x4 acc = (f32x4)(0.f);
        #pragma unroll
        for (int l = 0; l < L_DIM; ++l) {
            acc.x += bflo(v[l][0]); acc.y += bfhi(v[l][0]);
            acc.z += bflo(v[l][1]); acc.w += bfhi(v[l][1]);
        }
        const int n = n0 + c * CR + w_id;
        __builtin_nontemporal_store(acc,
            reinterpret_cast<f32x4*>(
                out + (size_t)n * D_DIM + col0 + lane * 4));
    };

    issue(0);
    issue(1);

#define STEP(c)                                   \
    {                                             \
        if ((c) + PFD < NCH) issue((c) + PFD);    \
        vm_wait<waitn(c)>();                      \
        consume(c);                               \
    }
    STEP(0)  STEP(1)  STEP(2)  STEP(3)
    STEP(4)  STEP(5)  STEP(6)  STEP(7)
    STEP(8)  STEP(9)  STEP(10) STEP(11)
    STEP(12) STEP(13) STEP(14) STEP(15)
#undef STEP
}

// ---- fallback: round-4 f32 kernel (used when ws too small) -------------
__global__ __launch_bounds__(256) void gather_sum_f32(
    const int* __restrict__ x,
    const float* __restrict__ w,
    float* __restrict__ out)
{
    __shared__ int sxi[128 * L_DIM];
    const int slice = blockIdx.x & 7;
    const int chunk = blockIdx.x >> 3;
    const int t     = threadIdx.x;
    const int n0    = chunk * 128;

    reinterpret_cast<int4*>(sxi)[t] =
        reinterpret_cast<const int4*>(x + (size_t)n0 * L_DIM)[t];
    __syncthreads();

    const int rg   = t >> 5;
    const int lane = t & 31;
    const int col  = slice * 128 + lane * 4;
    const float* __restrict__ wbase = w + col;

    #pragma unroll
    for (int i = 0; i < 8; ++i) {
        const int rA = rg + 16 * i;
        const int rB = rA + 8;
        const int* xA = sxi + rA * L_DIM;
        const int* xB = sxi + rB * L_DIM;
        f32x4 vA[L_DIM], vB[L_DIM];
        #pragma unroll
        for (int l = 0; l < L_DIM; ++l)
            vA[l] = *reinterpret_cast<const f32x4*>(
                wbase + (size_t)(l * K_DIM + xA[l]) * D_DIM);
        #pragma unroll
        for (int l = 0; l < L_DIM; ++l)
            vB[l] = *reinterpret_cast<const f32x4*>(
                wbase + (size_t)(l * K_DIM + xB[l]) * D_DIM);
        f32x4 accA = ((vA[0] + vA[1]) + (vA[2] + vA[3]))
                   + ((vA[4] + vA[5]) + (vA[6] + vA[7]));
        f32x4 accB = ((vB[0] + vB[1]) + (vB[2] + vB[3]))
                   + ((vB[4] + vB[5]) + (vB[6] + vB[7]));
        __builtin_nontemporal_store(accA,
            reinterpret_cast<f32x4*>(out + (size_t)(n0 + rA) * D_DIM + col));
        __builtin_nontemporal_store(accB,
            reinterpret_cast<f32x4*>(out + (size_t)(n0 + rB) * D_DIM + col));
    }
}

extern "C" void kernel_launch(void* const* d_in, const int* in_sizes, int n_in,
                              void* d_out, int out_size, void* d_ws, size_t ws_size,
                              hipStream_t stream)
{
    const int*   x = (const int*)d_in[0];     // (N, L) int32
    const float* w = (const float*)d_in[1];   // (L, K, D) f32
    float* out = (float*)d_out;               // (N, D) f32

    if (ws_size >= (size_t)W_ELEMS * 2) {
        unsigned short* wb = (unsigned short*)d_ws;
        convert_w_bf16<<<W_ELEMS / 4 / 256, 256, 0, stream>>>(w, wb);
        gather_sum_pipe<<<(N_ROWS / 128) * 8, 256, 0, stream>>>(x, wb, out);
    } else {
        gather_sum_f32<<<(N_ROWS / 128) * 8, 256, 0, stream>>>(x, w, out);
    }
}

// Round 11
// 145.357 us; speedup vs baseline: 1.0344x; 1.0344x over previous
//
#include <hip/hip_runtime.h>

// out[n, :] = sum_{l=0..7} weight[l, x[n,l], :]
// N=131072, L=8, K=1024, D=1024; f32 in/out.
//
// FINAL (round-9 kernel, 145.6 us): bf16 weight table in d_ws (halves the
// mandatory gather lines; absmax 0.0625 vs threshold 0.3175), XCD-sliced so
// each XCD's 2 MB table slice is L2-resident, channel-rotation spreads L2
// channels, zero-VGPR global_load_lds staging, barrier-free per-wave pipeline
// with counted vmcnt (prefetch depth 2, 3 LDS buffers), contiguous NT stores.
//
// Roofline: 41.5M mandatory L2 lines (33.5M read + 8M write) at the measured
// scattered-access rate of ~16 lines/cyc/XCD = 135 us + 9 us convert -> at
// the demonstrated ceiling within ~2%.

#define N_ROWS 131072
#define L_DIM 8
#define K_DIM 1024
#define D_DIM 1024

#define NXCD 8
#define RPB 128                      // output rows per block
#define CR 8                         // output rows per chunk
#define NCH (RPB / CR)               // 16 chunks
#define PFD 2                        // prefetch depth (chunks)
#define NBUF (PFD + 1)               // LDS buffers
#define CHB (CR * L_DIM * 256)       // bytes per chunk buffer = 16384
#define GRID_CHUNKS (N_ROWS / RPB)   // 1024
#define W_ELEMS (L_DIM * K_DIM * D_DIM)

typedef float        f32x4 __attribute__((ext_vector_type(4)));
typedef unsigned int u32x2 __attribute__((ext_vector_type(2)));

__device__ __forceinline__ unsigned short f2bf_rne(float f) {
    unsigned u = __float_as_uint(f);
    unsigned r = u + 0x7fffu + ((u >> 16) & 1u);   // round-to-nearest-even
    return (unsigned short)(r >> 16);
}
__device__ __forceinline__ float bflo(unsigned u) { return __uint_as_float(u << 16); }
__device__ __forceinline__ float bfhi(unsigned u) { return __uint_as_float(u & 0xffff0000u); }

__device__ __forceinline__ void load_lds16(const void* g, void* l) {
    __builtin_amdgcn_global_load_lds(
        (const __attribute__((address_space(1))) void*)g,
        (__attribute__((address_space(3))) void*)l,
        16, 0, 0);
}

template <int N>
__device__ __forceinline__ void vm_wait() {
    asm volatile("s_waitcnt vmcnt(%0)" :: "n"(N) : "memory");
    __builtin_amdgcn_sched_barrier(0);
}

// loads newer than chunk c's: chunks c+1..min(c+PFD,NCH-1), 4 instrs each;
// stores newer: min(PFD, c). (per-wave issue order: [4 loads][wait][store])
constexpr int waitn(int c) {
    int nl = (c + PFD <= NCH - 1) ? PFD : (NCH - 1 - c);
    int ns = (c < PFD) ? c : PFD;
    return 4 * nl + ns;
}

// ---- pass 1: f32 weight -> rotated bf16 scratch ------------------------
__global__ __launch_bounds__(256) void convert_w_bf16(
    const float* __restrict__ w, unsigned short* __restrict__ wb)
{
    const int i = blockIdx.x * 256 + threadIdx.x;       // 4 floats per thread
    const f32x4 v = __builtin_nontemporal_load(
        reinterpret_cast<const f32x4*>(w) + i);
    ushort4 o;
    o.x = f2bf_rne(v.x); o.y = f2bf_rne(v.y);
    o.z = f2bf_rne(v.z); o.w = f2bf_rne(v.w);

    const int rk = i >> 8;                              // (l,k) row id
    const int c0 = (i & 255) * 4;                       // col of first elem
    const int l  = rk >> 10;
    const int k  = rk & 1023;
    const int r  = (l + k) & 7;
    const int c2 = (c0 + r * 128) & 1023;               // rotated col
    *reinterpret_cast<ushort4*>(wb + ((size_t)rk << 10) + c2) = o;
}

// ---- pass 2: barrier-free pipelined gather+sum -------------------------
__global__ __launch_bounds__(256) void gather_sum_pipe(
    const int* __restrict__ x,
    const unsigned short* __restrict__ wb,
    float* __restrict__ out)
{
    __shared__ int sxi[RPB * L_DIM];                    // 4 KB indices
    __shared__ __align__(1024) char buf[NBUF * CHB];    // 3 x 16 KB

    const int slice = blockIdx.x & (NXCD - 1);          // -> XCD id
    const int chunk = blockIdx.x >> 3;
    const int t     = threadIdx.x;
    const int n0    = chunk * RPB;

    reinterpret_cast<int4*>(sxi)[t] =
        reinterpret_cast<const int4*>(x + (size_t)n0 * L_DIM)[t];
    __syncthreads();                                    // only barrier

    const int w_id = t >> 6;                            // wave 0..3
    const int lam  = t & 63;
    const int grp  = lam >> 4;                          // row within quad
    const int sub  = lam & 15;                          // 16 B unit in window
    const int half = (t >> 5) & 1;
    const int lane = t & 31;

    const char* __restrict__ wbytes = (const char*)wb;

    // issue chunk c's DMA: wave w stages gathered rows g in [16w, 16w+16)
    auto issue = [&](int c) {
        char* __restrict__ db = buf + (c % NBUF) * CHB;
        #pragma unroll
        for (int i = 0; i < 4; ++i) {
            const int j = w_id * 4 + i;                 // 0..15
            const int g = 4 * j + grp;                  // gathered row 0..63
            const int l = g & 7;
            const int k = sxi[c * 64 + g];
            const int r = (slice + l + k) & 7;          // rotated window
            const unsigned off =
                ((unsigned)((l << 10) + k) << 11) + ((unsigned)r << 8)
                + (unsigned)sub * 16u;
            load_lds16(wbytes + off, db + j * 1024);
        }
    };

    auto consume = [&](int c) {
        const char* __restrict__ rb = buf + (c % NBUF) * CHB;
        const int g0 = w_id * 16 + half * 8;            // wave-half's row base
        u32x2 v[L_DIM];
        #pragma unroll
        for (int l = 0; l < L_DIM; ++l)
            v[l] = *reinterpret_cast<const u32x2*>(
                rb + (g0 + l) * 256 + lane * 8);
        f32x4 acc = (f32x4)(0.f);
        #pragma unroll
        for (int l = 0; l < L_DIM; ++l) {
            acc.x += bflo(v[l][0]); acc.y += bfhi(v[l][0]);
            acc.z += bflo(v[l][1]); acc.w += bfhi(v[l][1]);
        }
        const int n = n0 + c * CR + 2 * w_id + half;
        __builtin_nontemporal_store(acc,
            reinterpret_cast<f32x4*>(
                out + (size_t)n * D_DIM + slice * 128 + lane * 4));
    };

    issue(0);
    issue(1);

#define STEP(c)                                   \
    {                                             \
        if ((c) + PFD < NCH) issue((c) + PFD);    \
        vm_wait<waitn(c)>();                      \
        consume(c);                               \
    }
    STEP(0)  STEP(1)  STEP(2)  STEP(3)
    STEP(4)  STEP(5)  STEP(6)  STEP(7)
    STEP(8)  STEP(9)  STEP(10) STEP(11)
    STEP(12) STEP(13) STEP(14) STEP(15)
#undef STEP
}

// ---- fallback: round-4 f32 kernel (used when ws too small) -------------
__global__ __launch_bounds__(256) void gather_sum_f32(
    const int* __restrict__ x,
    const float* __restrict__ w,
    float* __restrict__ out)
{
    __shared__ int sxi[RPB * L_DIM];
    const int slice = blockIdx.x & (NXCD - 1);
    const int chunk = blockIdx.x >> 3;
    const int t     = threadIdx.x;
    const int n0    = chunk * RPB;

    reinterpret_cast<int4*>(sxi)[t] =
        reinterpret_cast<const int4*>(x + (size_t)n0 * L_DIM)[t];
    __syncthreads();

    const int rg   = t >> 5;
    const int lane = t & 31;
    const int col  = slice * 128 + lane * 4;
    const float* __restrict__ wbase = w + col;

    #pragma unroll
    for (int i = 0; i < 8; ++i) {
        const int rA = rg + 16 * i;
        const int rB = rA + 8;
        const int* xA = sxi + rA * L_DIM;
        const int* xB = sxi + rB * L_DIM;
        f32x4 vA[L_DIM], vB[L_DIM];
        #pragma unroll
        for (int l = 0; l < L_DIM; ++l)
            vA[l] = *reinterpret_cast<const f32x4*>(
                wbase + (size_t)(l * K_DIM + xA[l]) * D_DIM);
        #pragma unroll
        for (int l = 0; l < L_DIM; ++l)
            vB[l] = *reinterpret_cast<const f32x4*>(
                wbase + (size_t)(l * K_DIM + xB[l]) * D_DIM);
        f32x4 accA = ((vA[0] + vA[1]) + (vA[2] + vA[3]))
                   + ((vA[4] + vA[5]) + (vA[6] + vA[7]));
        f32x4 accB = ((vB[0] + vB[1]) + (vB[2] + vB[3]))
                   + ((vB[4] + vB[5]) + (vB[6] + vB[7]));
        __builtin_nontemporal_store(accA,
            reinterpret_cast<f32x4*>(out + (size_t)(n0 + rA) * D_DIM + col));
        __builtin_nontemporal_store(accB,
            reinterpret_cast<f32x4*>(out + (size_t)(n0 + rB) * D_DIM + col));
    }
}

extern "C" void kernel_launch(void* const* d_in, const int* in_sizes, int n_in,
                              void* d_out, int out_size, void* d_ws, size_t ws_size,
                              hipStream_t stream)
{
    const int*   x = (const int*)d_in[0];     // (N, L) int32
    const float* w = (const float*)d_in[1];   // (L, K, D) f32
    float* out = (float*)d_out;               // (N, D) f32

    if (ws_size >= (size_t)W_ELEMS * 2) {
        unsigned short* wb = (unsigned short*)d_ws;
        convert_w_bf16<<<W_ELEMS / 4 / 256, 256, 0, stream>>>(w, wb);
        gather_sum_pipe<<<GRID_CHUNKS * NXCD, 256, 0, stream>>>(x, wb, out);
    } else {
        gather_sum_f32<<<GRID_CHUNKS * NXCD, 256, 0, stream>>>(x, w, out);
    }
}